// Round 13
// baseline (425.912 us; speedup 1.0000x reference)
//
#include <hip/hip_runtime.h>
#include <math.h>

// TreeLSTM MI355X — R25: de-contend repFold atomics; deepen lvl8_cell MLP.
// R24 post-mortem (416.2us, -40): rep-fold deletion was a bigger win than the
// counter table showed, but lvl7 regressed 70.9->77.1us — ldsRep atomicAdd is
// 8-way contended (4 q-sublanes x 2 waveR waves share each c). R25:
//  1) fold rsum across q via __shfl_xor(16|32); only q==0 lanes hit ldsRep ->
//     2-way contention (free per bank rules), 4x fewer LDS atomics.
//  2) lvl8_cell unroll 4->8 (VGPR 16, occ 68% => free MLP on the L3 gather).
// No structural changes (6/6 restructuring rounds failed; R18-R21/R24 wins
// were all work-removal). Layout unchanged (233.18 MB).

typedef _Float16 h16;
typedef h16 f16x8 __attribute__((ext_vector_type(8)));
typedef h16 h16x4 __attribute__((ext_vector_type(4)));
typedef float f32x4 __attribute__((ext_vector_type(4)));

#define HS 256
#define NTREE 1023
#define B2 256

#define DMA16(gp, lp) __builtin_amdgcn_global_load_lds( \
    (const __attribute__((address_space(1))) void*)(gp), \
    (__attribute__((address_space(3))) void*)(lp), 16, 0, 0)

__device__ __forceinline__ float sigf(float x){
  return __builtin_amdgcn_rcpf(1.0f + exp2f(x * -1.44269504f));
}
// sigmoid(a)*tanh(b) in 3 trans (exp2,exp2,rcp). Clamp avoids E2=inf -> NaN.
__device__ __forceinline__ float sig_mul_tanh(float a, float b){
  const float E1 = exp2f(a * -1.44269504f);
  const float E2 = exp2f(fminf(b * -2.88539008f, 126.0f));
  return (1.0f - E2) * __builtin_amdgcn_rcpf((1.0f + E1) * (1.0f + E2));
}

// ------------- convert fp32 -> fp16 (emb, Ufw, Uiou, Wiou) + zero rep -------
__global__ __launch_bounds__(256) void convert_all(const float* __restrict__ emb,
    const float* __restrict__ Ufw, const float* __restrict__ Uiou,
    const float* __restrict__ Wiou, h16* __restrict__ emb16,
    h16* __restrict__ W16, h16* __restrict__ Wx16, float* __restrict__ rep){
  if (blockIdx.x < 64)
    ((float4*)rep)[blockIdx.x*256 + threadIdx.x] = make_float4(0.f,0.f,0.f,0.f);
  const size_t i0 = ((size_t)blockIdx.x*256 + threadIdx.x)*8;
  const float* src; h16* dst; size_t off;
  if (i0 < 8192000UL){ src = emb;  dst = emb16;       off = i0; }
  else if (i0 < 8257536UL){ src = Ufw;  dst = W16;        off = i0 - 8192000UL; }
  else if (i0 < 8454144UL){ src = Uiou; dst = W16+65536;  off = i0 - 8257536UL; }
  else               { src = Wiou; dst = Wx16;       off = i0 - 8454144UL; }
  const float4 v0 = *(const float4*)&src[off];
  const float4 v1 = *(const float4*)&src[off+4];
  f16x8 o;
  o[0]=(h16)v0.x; o[1]=(h16)v0.y; o[2]=(h16)v0.z; o[3]=(h16)v0.w;
  o[4]=(h16)v1.x; o[5]=(h16)v1.y; o[6]=(h16)v1.z; o[7]=(h16)v1.w;
  *(f16x8*)&dst[off] = o;
}

// ------------- swizzle W16 -> Wfrag (4 gates) and Wx16 -> WxFrag (3 gates) --
__global__ __launch_bounds__(256) void swizzle_all(const h16* __restrict__ W16,
    const h16* __restrict__ Wx16, h16* __restrict__ Wfrag,
    h16* __restrict__ WxFrag){
  const int tid = blockIdx.x*256 + threadIdx.x;   // 0..90111
  if (tid < 65536){
    const int lane = tid & 63;
    const int f    = (tid >> 6) & 15;
    const int kc   = (tid >> 10) & 7;
    const int cb   = tid >> 13;
    const int g = f >> 2, cf = f & 3;
    const int row = g*256 + cb*64 + cf*16 + (lane & 15);
    const int col = kc*32 + (lane >> 4)*8;
    const f16x8 v = *(const f16x8*)&W16[(size_t)row*256 + col];
    *(f16x8*)&Wfrag[(size_t)tid*8] = v;
  } else {
    const int t2 = tid - 65536;          // 0..24575
    const int lane = t2 & 63;
    const int frag = t2 >> 6;            // 0..383 = cb*96 + kc*12 + f
    const int cb  = frag / 96;
    const int rem = frag % 96;
    const int kc  = rem / 12;
    const int f   = rem % 12;
    const int g = f >> 2, cf = f & 3;    // g in {0,1,2} = i,o,u
    const int row = g*256 + cb*64 + cf*16 + (lane & 15);
    const int col = kc*32 + (lane >> 4)*8;
    const f16x8 v = *(const f16x8*)&Wx16[(size_t)row*256 + col];
    *(f16x8*)&WxFrag[(size_t)frag*512 + lane*8] = v;
  }
}

// ------------- hT,cT = leaf cell(emb @ Wx^T + b) per TYPE (fused) -----------
__global__ __launch_bounds__(256,3) void ht_mfma(const h16* __restrict__ emb16,
    const h16* __restrict__ WxFrag, const float* __restrict__ biou,
    h16* __restrict__ hT, h16* __restrict__ cT){
  __shared__ h16 ldsA[4*8*64*8];   // 32 KB
  __shared__ h16 ldsB[12*64*8];    // 12 KB
  const int t = threadIdx.x, w = t >> 6, l = t & 63;
  const int q = l >> 4, li = l & 15;
  const int waveR = w & 1, waveC = w >> 1;
  const int bx = blockIdx.x;

  {
    const int grow = bx*64 + w*16 + li;
    const size_t abase = (size_t)grow * 256;
    #pragma unroll
    for (int kc=0; kc<8; ++kc)
      DMA16(emb16 + abase + kc*32 + q*8, &ldsA[(w*8 + kc)*512]);
  }

  for (int cb=0; cb<4; ++cb){
    const h16* wfBase = WxFrag + (size_t)cb*8*12*512 + (size_t)l*8;

    #pragma unroll
    for (int i=0; i<3; ++i)
      DMA16(wfBase + ((size_t)(w*3 + i))*512, &ldsB[(w*3 + i)*512]);
    __syncthreads();   // drains A (cb0) + B(0)

    f32x4 acc[3][2][2] = {};   // [gate i,o,u][rt][ct]
    #pragma unroll
    for (int kc=0; kc<8; ++kc){
      f16x8 aF[2], bF[3][2];
      #pragma unroll
      for (int rt=0; rt<2; ++rt)
        aF[rt] = *(const f16x8*)&ldsA[(((waveR*2 + rt)*8 + kc)*64 + l)*8];
      #pragma unroll
      for (int g=0; g<3; ++g)
        #pragma unroll
        for (int ct=0; ct<2; ++ct)
          bF[g][ct] = *(const f16x8*)&ldsB[((g*4 + waveC*2 + ct)*64 + l)*8];
      __syncthreads();   // reads done
      if (kc < 7){
        #pragma unroll
        for (int i=0; i<3; ++i)
          DMA16(wfBase + ((size_t)(kc+1)*12 + w*3 + i)*512,
                &ldsB[(w*3 + i)*512]);
      }
      #pragma unroll
      for (int g=0; g<3; ++g)
        #pragma unroll
        for (int rt=0; rt<2; ++rt)
          #pragma unroll
          for (int ct=0; ct<2; ++ct)
            acc[g][rt][ct] = __builtin_amdgcn_mfma_f32_16x16x32_f16(
                aF[rt], bF[g][ct], acc[g][rt][ct], 0,0,0);
      __syncthreads();   // drains B(kc+1)
    }

    // epilogue: leaf cell from f32 pre-acts, write hT/cT
    #pragma unroll
    for (int ct=0; ct<2; ++ct){
      const int c = cb*64 + waveC*32 + ct*16 + li;
      const float bi = biou[c], bo = biou[256+c], bu = biou[512+c];
      #pragma unroll
      for (int rt=0; rt<2; ++rt){
        #pragma unroll
        for (int reg=0; reg<4; ++reg){
          const int row = bx*64 + waveR*32 + rt*16 + q*4 + reg;
          const float iv = acc[0][rt][ct][reg] + bi;
          const float ov = acc[1][rt][ct][reg] + bo;
          const float uv = acc[2][rt][ct][reg] + bu;
          const float cc = sig_mul_tanh(iv, uv);
          const float hh = sig_mul_tanh(ov, cc);
          hT[(size_t)row*256 + c] = (h16)hh;
          cT[(size_t)row*256 + c] = (h16)cc;
        }
      }
    }
  }
}

// ------------- GT16 = [Ufw;Uiou] @ hT^T per type, h16x4 interleaved ---------
__global__ __launch_bounds__(256,3) void gt16_mfma(const h16* __restrict__ hT,
    const h16* __restrict__ Wfrag, const float* __restrict__ biou,
    const float* __restrict__ Ufb, h16* __restrict__ GT16){
  __shared__ h16 ldsA[4*8*64*8];   // 32 KB
  __shared__ h16 ldsB[16*64*8];    // 16 KB
  const int t = threadIdx.x, w = t >> 6, l = t & 63;
  const int q = l >> 4, li = l & 15;
  const int waveR = w & 1, waveC = w >> 1;
  const int bx = blockIdx.x;

  {
    const int grow = bx*64 + w*16 + li;
    const size_t abase = (size_t)grow * 256;
    #pragma unroll
    for (int kc=0; kc<8; ++kc)
      DMA16(hT + abase + kc*32 + q*8, &ldsA[(w*8 + kc)*512]);
  }

  for (int cb=0; cb<4; ++cb){
    const h16* wfBase = Wfrag + (size_t)cb*8*16*512 + (size_t)l*8;

    #pragma unroll
    for (int i=0; i<4; ++i)
      DMA16(wfBase + ((size_t)(w*4 + i))*512, &ldsB[(w*4 + i)*512]);
    __syncthreads();

    f32x4 acc[4][2][2] = {};
    #pragma unroll
    for (int kc=0; kc<8; ++kc){
      f16x8 aF[2], bF[4][2];
      #pragma unroll
      for (int rt=0; rt<2; ++rt)
        aF[rt] = *(const f16x8*)&ldsA[(((waveR*2 + rt)*8 + kc)*64 + l)*8];
      #pragma unroll
      for (int g=0; g<4; ++g)
        #pragma unroll
        for (int ct=0; ct<2; ++ct)
          bF[g][ct] = *(const f16x8*)&ldsB[((g*4 + waveC*2 + ct)*64 + l)*8];
      __syncthreads();
      if (kc < 7){
        #pragma unroll
        for (int i=0; i<4; ++i)
          DMA16(wfBase + ((size_t)(kc+1)*16 + w*4 + i)*512,
                &ldsB[(w*4 + i)*512]);
      }
      #pragma unroll
      for (int g=0; g<4; ++g)
        #pragma unroll
        for (int rt=0; rt<2; ++rt)
          #pragma unroll
          for (int ct=0; ct<2; ++ct)
            acc[g][rt][ct] = __builtin_amdgcn_mfma_f32_16x16x32_f16(
                aF[rt], bF[g][ct], acc[g][rt][ct], 0,0,0);
      __syncthreads();
    }

    #pragma unroll
    for (int ct=0; ct<2; ++ct){
      const int c = cb*64 + waveC*32 + ct*16 + li;
      const float fb  = Ufb[c];
      const float bi2 = 0.5f*biou[c], bo2 = 0.5f*biou[256+c], bu2 = 0.5f*biou[512+c];
      #pragma unroll
      for (int rt=0; rt<2; ++rt){
        #pragma unroll
        for (int reg=0; reg<4; ++reg){
          const int row = bx*64 + waveR*32 + rt*16 + q*4 + reg;
          h16x4 o;
          o[0] = (h16)(acc[0][rt][ct][reg] + fb);
          o[1] = (h16)(acc[1][rt][ct][reg] + bi2);
          o[2] = (h16)(acc[2][rt][ct][reg] + bo2);
          o[3] = (h16)(acc[3][rt][ct][reg] + bu2);
          *(h16x4*)&GT16[(size_t)row*1024 + c*4] = o;
        }
      }
    }
  }
}

// ------------- lvl8: gather+cell + leaf-rep + parent-rep fold ---------------
__global__ __launch_bounds__(256) void lvl8_cell(const int* __restrict__ t1,
    const int* __restrict__ t2, const h16* __restrict__ GT16,
    const h16* __restrict__ cT, const h16* __restrict__ hT,
    h16* __restrict__ hUpHigh, h16* __restrict__ cPar,
    float* __restrict__ rep){
  const int k = threadIdx.x;
  const int m0 = blockIdx.x*32;
  const int rr = m0 >> 8;
  const int* tp = (rr < 128) ? t1 : t2;
  const int b = rr & 127;
  float s = 0.f;
  #pragma unroll 8
  for (int p=0; p<32; ++p){
    const int m = m0 + p, jn = m & 255;
    const size_t vl = (size_t)tp[b*NTREE + 511 + 2*jn];
    const size_t vr = (size_t)tp[b*NTREE + 512 + 2*jn];
    const h16x4 gl = *(const h16x4*)&GT16[vl*1024 + k*4];
    const h16x4 gr = *(const h16x4*)&GT16[vr*1024 + k*4];
    const float cl = (float)cT[vl*256 + k];
    const float cr = (float)cT[vr*256 + k];
    const float fl = sigf((float)gl[0]);
    const float fr = sigf((float)gr[0]);
    const float iv = (float)gl[1] + (float)gr[1];
    const float ov = (float)gl[2] + (float)gr[2];
    const float uv = (float)gl[3] + (float)gr[3];
    const float cnew = sig_mul_tanh(iv, uv) + fl*cl + fr*cr;
    const float hnew = sig_mul_tanh(ov, cnew);
    hUpHigh[((size_t)jn*256 + rr)*256 + k] = (h16)hnew;
    cPar[(size_t)m*256 + k] = (h16)cnew;
    s += (float)hT[vl*256 + k] + (float)hT[vr*256 + k] + hnew;  // leaves + parent
  }
  atomicAdd(&rep[rr*HS + k], s);
}

// ------------- level kernel (non-leaf levels, proven R18 schedule) ----------
// repFold (log2n>=5 only): rr2 = (bx*32)>>log2n is block-constant; fold
// per-thread h-sums across the 4 q-sublanes (shfl_xor 16,32 — lanes sharing
// the same c), then only q==0 lanes touch ldsRep (2-way, free), one global
// atomicAdd per (block,col).
__global__ __launch_bounds__(256,3) void level_mfma(
    const h16* __restrict__ hChild, const h16* __restrict__ cChild,
    const h16* __restrict__ Wfrag,   // [cb=4][kc=8][f=16][lane=64][8]
    const float* __restrict__ biou, const float* __restrict__ Ufb,
    h16* __restrict__ hUpW, h16* __restrict__ cPar, float* __restrict__ rep,
    int log2n, int cbN, int cOff, int ndOff, int repFold){
  const int n = 1 << log2n;
  const int mask2 = 2*n - 1;
  __shared__ h16 ldsA[4*8*64*8];   // 32 KB
  __shared__ h16 ldsB[16*64*8];    // 16 KB
  __shared__ float ldsRep[256];    //  1 KB
  const int t = threadIdx.x, w = t >> 6, l = t & 63;
  const int q = l >> 4, li = l & 15;
  const int waveR = w & 1, waveC = w >> 1;
  const int bx = blockIdx.x;

  if (repFold) ldsRep[t] = 0.f;    // first __syncthreads orders vs epilogue

  // ---- stage A once: wave w stages rowFrag R=w, kc=0..7 (frag-order) ----
  {
    const int grow = bx*64 + w*16 + li;
    const int cidx = grow & mask2;
    const int rr   = grow >> (log2n + 1);
    const size_t abase = ((size_t)(cOff + cidx)*256 + rr)*256;
    #pragma unroll
    for (int kc=0; kc<8; ++kc)
      DMA16(hChild + abase + kc*32 + q*8, &ldsA[(w*8 + kc)*512]);
  }

  for (int cb=0; cb<cbN; ++cb){
    const int cbi = blockIdx.y*cbN + cb;            // 64-col group 0..3
    const int colBase = cbi*64;
    const h16* wfBase = Wfrag + (size_t)cbi*8*16*512 + (size_t)l*8;

    // prologue: DMA B(kc=0)
    #pragma unroll
    for (int i=0; i<4; ++i)
      DMA16(wfBase + ((size_t)(w*4 + i))*512, &ldsB[(w*4 + i)*512]);
    __syncthreads();   // drains A-DMA (cb==0) + B(0) + prior epilogue reads

    f32x4 acc[4][2][2] = {};   // [gate f,i,o,u][rt][ct]
    #pragma unroll
    for (int kc=0; kc<8; ++kc){
      f16x8 aF[2], bF[4][2];
      #pragma unroll
      for (int rt=0; rt<2; ++rt)
        aF[rt] = *(const f16x8*)&ldsA[(((waveR*2 + rt)*8 + kc)*64 + l)*8];
      #pragma unroll
      for (int g=0; g<4; ++g)
        #pragma unroll
        for (int ct=0; ct<2; ++ct)
          bF[g][ct] = *(const f16x8*)&ldsB[((g*4 + waveC*2 + ct)*64 + l)*8];
      __syncthreads();   // all reads done
      if (kc < 7){
        #pragma unroll
        for (int i=0; i<4; ++i)
          DMA16(wfBase + ((size_t)(kc+1)*16 + w*4 + i)*512,
                &ldsB[(w*4 + i)*512]);
      }
      #pragma unroll
      for (int g=0; g<4; ++g)
        #pragma unroll
        for (int rt=0; rt<2; ++rt)
          #pragma unroll
          for (int ct=0; ct<2; ++ct)
            acc[g][rt][ct] = __builtin_amdgcn_mfma_f32_16x16x32_f16(
                aF[rt], bF[g][ct], acc[g][rt][ct], 0,0,0);
      __syncthreads();   // drains B(kc+1)
    }

    // ---- epilogue (all lane-local; sibling pairs = adjacent C regs) ----
    #pragma unroll
    for (int ct=0; ct<2; ++ct){
      const int c = colBase + waveC*32 + ct*16 + li;
      const float fb  = Ufb[c];
      const float bi_ = biou[c], bo_ = biou[256+c], bu_ = biou[512+c];
      float rsum = 0.f;
      #pragma unroll
      for (int rt=0; rt<2; ++rt){
        #pragma unroll
        for (int pp=0; pp<2; ++pp){
          const int crel = waveR*32 + rt*16 + q*4 + 2*pp;  // even child row (rel)
          const int m = bx*32 + (crel >> 1);               // global parent index
          const int rr2 = m >> log2n;
          const int jn = m & (n - 1);
          const float cl = (float)cChild[(size_t)(bx*64 + crel)*256 + c];
          const float cr = (float)cChild[(size_t)(bx*64 + crel + 1)*256 + c];
          const float fl = sigf(acc[0][rt][ct][2*pp]   + fb);
          const float fr = sigf(acc[0][rt][ct][2*pp+1] + fb);
          const float iv = acc[1][rt][ct][2*pp] + acc[1][rt][ct][2*pp+1] + bi_;
          const float ov = acc[2][rt][ct][2*pp] + acc[2][rt][ct][2*pp+1] + bo_;
          const float uv = acc[3][rt][ct][2*pp] + acc[3][rt][ct][2*pp+1] + bu_;
          const float cnew = sig_mul_tanh(iv, uv) + fl*cl + fr*cr;
          const float hnew = sig_mul_tanh(ov, cnew);
          hUpW[(((size_t)(ndOff + jn))*256 + rr2)*256 + c] = (h16)hnew;
          cPar[((size_t)m)*256 + c] = (h16)cnew;
          rsum += hnew;
        }
      }
      if (repFold){
        // fold across the 4 q-sublanes sharing this c (l, l^16, l^32, l^48)
        rsum += __shfl_xor(rsum, 16, 64);
        rsum += __shfl_xor(rsum, 32, 64);
        if (q == 0) atomicAdd(&ldsRep[c], rsum);   // 2 writers (waveR pair)
      }
    }
  }

  if (repFold){
    __syncthreads();
    atomicAdd(&rep[((bx*32) >> log2n)*HS + t], ldsRep[t]);
  }
}

// ------------- rep accumulation (lvl<=4 outputs, nodes 0..30 only) ----------
__global__ __launch_bounds__(256) void rep_accum(const h16* __restrict__ H,
    float* __restrict__ rep, int nrows, int chunk){
  const int r = blockIdx.y, k = threadIdx.x;
  const int n0 = blockIdx.x * chunk;
  int n1 = n0 + chunk; if (n1 > nrows) n1 = nrows;
  float s = 0.f;
  for (int nd = n0; nd < n1; ++nd)
    s += (float)H[((size_t)nd*256 + r)*HS + k];
  atomicAdd(&rep[r*HS + k], s);
}

// ------------- classifier -------------
__global__ __launch_bounds__(256) void cls_kernel(const float* __restrict__ rep,
    const float* __restrict__ clsw, const float* __restrict__ clsb,
    float* __restrict__ out){
  const int b = blockIdx.x, k = threadIdx.x;
  const float d = fabsf(rep[b*HS + k] - rep[(128+b)*HS + k]) * (1.0f/1023.0f);
  __shared__ float r0[256], r1[256];
  r0[k] = d * clsw[k];
  r1[k] = d * clsw[HS + k];
  __syncthreads();
  for (int off = 128; off > 0; off >>= 1){
    if (k < off){ r0[k] += r0[k+off]; r1[k] += r1[k+off]; }
    __syncthreads();
  }
  if (k == 0){
    out[b*2 + 0] = r0[0] + clsb[0];
    out[b*2 + 1] = r1[0] + clsb[1];
  }
}

extern "C" void kernel_launch(void* const* d_in, const int* in_sizes, int n_in,
                              void* d_out, int out_size, void* d_ws, size_t ws_size,
                              hipStream_t stream){
  const int*   types1 = (const int*)d_in[0];
  const int*   types2 = (const int*)d_in[1];
  const float* emb    = (const float*)d_in[2];
  const float* Wiou   = (const float*)d_in[3];
  const float* Uiou   = (const float*)d_in[4];
  const float* biou   = (const float*)d_in[5];
  const float* Ufw    = (const float*)d_in[6];
  const float* Ufb    = (const float*)d_in[7];
  const float* clsw   = (const float*)d_in[8];
  const float* clsb   = (const float*)d_in[9];
  float* out = (float*)d_out;

  // ---- overlay layout (h16 units). Total 116,588,544 h16 = 233.18 MB ----
  h16* ws      = (h16*)d_ws;
  // GT16 [0, 32,768,000) overlays emb16 (dead after ht_mfma);
  // hUpLow+cB overlay GT16 (dead after lvl8_cell).
  h16* GT16    = ws;                         // 32,768,000 h16 = 65.5 MB
  h16* emb16   = ws + 24576000UL;            //  8,192,000
  h16* Wx16    = ws + 32768000UL;            //    196,608 (dead after swizzle)
  h16* hUpLow  = ws;                         // 16,711,680 (nodes 0..254)
  h16* cB      = ws + 16711680UL;            //  8,388,608
  h16* hT      = ws + 65536000UL;            //  8,192,000
  h16* cT      = ws + 73728000UL;            //  8,192,000
  h16* hUpHigh = ws + 81920000UL;            // 16,777,216 (nodes 255..510 local)
  h16* cA      = ws + 98697216UL;            // 16,777,216
  h16* W16     = ws + 115474432UL;           //    262,144
  h16* Wfrag   = ws + 115736576UL;           //    524,288
  float* rep   = (float*)(ws + 116260864UL); //     65,536 f32
  h16* WxFrag  = ws + 116391936UL;           //    196,608

  convert_all<<<4224, 256, 0, stream>>>(emb, Ufw, Uiou, Wiou, emb16, W16, Wx16, rep);
  swizzle_all<<<352, 256, 0, stream>>>(W16, Wx16, Wfrag, WxFrag);
  ht_mfma<<<500, 256, 0, stream>>>(emb16, WxFrag, biou, hT, cT);
  gt16_mfma<<<500, 256, 0, stream>>>(hT, Wfrag, biou, Ufb, GT16); // overwrites emb16
  lvl8_cell<<<2048, 256, 0, stream>>>(types1, types2, GT16, cT, hT,
                                      hUpHigh, cA, rep);

  const h16* cprev = cA;
  for (int lvl = 7; lvl >= 0; --lvl){
    const int children = 512 << lvl;        // B2 * 2n
    const int cbN = (lvl >= 6) ? 4 : 1;     // big levels: y=1, col loop in-block
    h16* cout = ((8 - lvl) & 1) ? cB : cA;
    const h16* hin = (lvl == 7) ? hUpHigh : hUpLow;
    const int cOff  = (lvl == 7) ? 0 : ((1 << (lvl + 1)) - 1);
    const int ndOff = (1 << lvl) - 1;
    const int repFold = (lvl >= 5) ? 1 : 0; // rr2 block-constant iff log2n>=5
    level_mfma<<<dim3(children/64, 4/cbN), 256, 0, stream>>>(
        hin, cprev, Wfrag, biou, Ufb, hUpLow, cout, rep,
        lvl, cbN, cOff, ndOff, repFold);
    cprev = cout;
  }
  // only lvl<=4 outputs (nodes 0..30) still need scanning
  rep_accum<<<dim3(1, B2), 256, 0, stream>>>(hUpLow, rep, 31, 31);
  cls_kernel<<<128, 256, 0, stream>>>(rep, clsw, clsb, out);
}

// Round 14
// 418.033 us; speedup vs baseline: 1.0188x; 1.0188x over previous
//
#include <hip/hip_runtime.h>
#include <math.h>

// TreeLSTM MI355X — R26: disentangle R25's bundle.
// R25 post-mortem (425.9, +9.7): the shfl_xor repFold fold REGRESSED lvl7
// 77.1->91.2us (ds_permute sits on the lgkmcnt pipe inside the epilogue,
// serializing vs stores + next-cb DMA) — worse than the 8-way ldsRep atomic
// it replaced. But the 3 repFold levels regressed ~+24us while total moved
// only +9.7 => the bundled lvl8_cell unroll 4->8 likely helped ~10-15us.
// R26: revert level_mfma repFold to R24's plain inline ldsRep atomicAdd
// (proven 77.1us lvl7), KEEP lvl8_cell unroll 8. Single-variable edit.
// Pre-committed decision rule: >=414us => R24 config is converged; declare
// plateau next round. Layout unchanged (233.18 MB).

typedef _Float16 h16;
typedef h16 f16x8 __attribute__((ext_vector_type(8)));
typedef h16 h16x4 __attribute__((ext_vector_type(4)));
typedef float f32x4 __attribute__((ext_vector_type(4)));

#define HS 256
#define NTREE 1023
#define B2 256

#define DMA16(gp, lp) __builtin_amdgcn_global_load_lds( \
    (const __attribute__((address_space(1))) void*)(gp), \
    (__attribute__((address_space(3))) void*)(lp), 16, 0, 0)

__device__ __forceinline__ float sigf(float x){
  return __builtin_amdgcn_rcpf(1.0f + exp2f(x * -1.44269504f));
}
// sigmoid(a)*tanh(b) in 3 trans (exp2,exp2,rcp). Clamp avoids E2=inf -> NaN.
__device__ __forceinline__ float sig_mul_tanh(float a, float b){
  const float E1 = exp2f(a * -1.44269504f);
  const float E2 = exp2f(fminf(b * -2.88539008f, 126.0f));
  return (1.0f - E2) * __builtin_amdgcn_rcpf((1.0f + E1) * (1.0f + E2));
}

// ------------- convert fp32 -> fp16 (emb, Ufw, Uiou, Wiou) + zero rep -------
__global__ __launch_bounds__(256) void convert_all(const float* __restrict__ emb,
    const float* __restrict__ Ufw, const float* __restrict__ Uiou,
    const float* __restrict__ Wiou, h16* __restrict__ emb16,
    h16* __restrict__ W16, h16* __restrict__ Wx16, float* __restrict__ rep){
  if (blockIdx.x < 64)
    ((float4*)rep)[blockIdx.x*256 + threadIdx.x] = make_float4(0.f,0.f,0.f,0.f);
  const size_t i0 = ((size_t)blockIdx.x*256 + threadIdx.x)*8;
  const float* src; h16* dst; size_t off;
  if (i0 < 8192000UL){ src = emb;  dst = emb16;       off = i0; }
  else if (i0 < 8257536UL){ src = Ufw;  dst = W16;        off = i0 - 8192000UL; }
  else if (i0 < 8454144UL){ src = Uiou; dst = W16+65536;  off = i0 - 8257536UL; }
  else               { src = Wiou; dst = Wx16;       off = i0 - 8454144UL; }
  const float4 v0 = *(const float4*)&src[off];
  const float4 v1 = *(const float4*)&src[off+4];
  f16x8 o;
  o[0]=(h16)v0.x; o[1]=(h16)v0.y; o[2]=(h16)v0.z; o[3]=(h16)v0.w;
  o[4]=(h16)v1.x; o[5]=(h16)v1.y; o[6]=(h16)v1.z; o[7]=(h16)v1.w;
  *(f16x8*)&dst[off] = o;
}

// ------------- swizzle W16 -> Wfrag (4 gates) and Wx16 -> WxFrag (3 gates) --
__global__ __launch_bounds__(256) void swizzle_all(const h16* __restrict__ W16,
    const h16* __restrict__ Wx16, h16* __restrict__ Wfrag,
    h16* __restrict__ WxFrag){
  const int tid = blockIdx.x*256 + threadIdx.x;   // 0..90111
  if (tid < 65536){
    const int lane = tid & 63;
    const int f    = (tid >> 6) & 15;
    const int kc   = (tid >> 10) & 7;
    const int cb   = tid >> 13;
    const int g = f >> 2, cf = f & 3;
    const int row = g*256 + cb*64 + cf*16 + (lane & 15);
    const int col = kc*32 + (lane >> 4)*8;
    const f16x8 v = *(const f16x8*)&W16[(size_t)row*256 + col];
    *(f16x8*)&Wfrag[(size_t)tid*8] = v;
  } else {
    const int t2 = tid - 65536;          // 0..24575
    const int lane = t2 & 63;
    const int frag = t2 >> 6;            // 0..383 = cb*96 + kc*12 + f
    const int cb  = frag / 96;
    const int rem = frag % 96;
    const int kc  = rem / 12;
    const int f   = rem % 12;
    const int g = f >> 2, cf = f & 3;    // g in {0,1,2} = i,o,u
    const int row = g*256 + cb*64 + cf*16 + (lane & 15);
    const int col = kc*32 + (lane >> 4)*8;
    const f16x8 v = *(const f16x8*)&Wx16[(size_t)row*256 + col];
    *(f16x8*)&WxFrag[(size_t)frag*512 + lane*8] = v;
  }
}

// ------------- hT,cT = leaf cell(emb @ Wx^T + b) per TYPE (fused) -----------
__global__ __launch_bounds__(256,3) void ht_mfma(const h16* __restrict__ emb16,
    const h16* __restrict__ WxFrag, const float* __restrict__ biou,
    h16* __restrict__ hT, h16* __restrict__ cT){
  __shared__ h16 ldsA[4*8*64*8];   // 32 KB
  __shared__ h16 ldsB[12*64*8];    // 12 KB
  const int t = threadIdx.x, w = t >> 6, l = t & 63;
  const int q = l >> 4, li = l & 15;
  const int waveR = w & 1, waveC = w >> 1;
  const int bx = blockIdx.x;

  {
    const int grow = bx*64 + w*16 + li;
    const size_t abase = (size_t)grow * 256;
    #pragma unroll
    for (int kc=0; kc<8; ++kc)
      DMA16(emb16 + abase + kc*32 + q*8, &ldsA[(w*8 + kc)*512]);
  }

  for (int cb=0; cb<4; ++cb){
    const h16* wfBase = WxFrag + (size_t)cb*8*12*512 + (size_t)l*8;

    #pragma unroll
    for (int i=0; i<3; ++i)
      DMA16(wfBase + ((size_t)(w*3 + i))*512, &ldsB[(w*3 + i)*512]);
    __syncthreads();   // drains A (cb0) + B(0)

    f32x4 acc[3][2][2] = {};   // [gate i,o,u][rt][ct]
    #pragma unroll
    for (int kc=0; kc<8; ++kc){
      f16x8 aF[2], bF[3][2];
      #pragma unroll
      for (int rt=0; rt<2; ++rt)
        aF[rt] = *(const f16x8*)&ldsA[(((waveR*2 + rt)*8 + kc)*64 + l)*8];
      #pragma unroll
      for (int g=0; g<3; ++g)
        #pragma unroll
        for (int ct=0; ct<2; ++ct)
          bF[g][ct] = *(const f16x8*)&ldsB[((g*4 + waveC*2 + ct)*64 + l)*8];
      __syncthreads();   // reads done
      if (kc < 7){
        #pragma unroll
        for (int i=0; i<3; ++i)
          DMA16(wfBase + ((size_t)(kc+1)*12 + w*3 + i)*512,
                &ldsB[(w*3 + i)*512]);
      }
      #pragma unroll
      for (int g=0; g<3; ++g)
        #pragma unroll
        for (int rt=0; rt<2; ++rt)
          #pragma unroll
          for (int ct=0; ct<2; ++ct)
            acc[g][rt][ct] = __builtin_amdgcn_mfma_f32_16x16x32_f16(
                aF[rt], bF[g][ct], acc[g][rt][ct], 0,0,0);
      __syncthreads();   // drains B(kc+1)
    }

    // epilogue: leaf cell from f32 pre-acts, write hT/cT
    #pragma unroll
    for (int ct=0; ct<2; ++ct){
      const int c = cb*64 + waveC*32 + ct*16 + li;
      const float bi = biou[c], bo = biou[256+c], bu = biou[512+c];
      #pragma unroll
      for (int rt=0; rt<2; ++rt){
        #pragma unroll
        for (int reg=0; reg<4; ++reg){
          const int row = bx*64 + waveR*32 + rt*16 + q*4 + reg;
          const float iv = acc[0][rt][ct][reg] + bi;
          const float ov = acc[1][rt][ct][reg] + bo;
          const float uv = acc[2][rt][ct][reg] + bu;
          const float cc = sig_mul_tanh(iv, uv);
          const float hh = sig_mul_tanh(ov, cc);
          hT[(size_t)row*256 + c] = (h16)hh;
          cT[(size_t)row*256 + c] = (h16)cc;
        }
      }
    }
  }
}

// ------------- GT16 = [Ufw;Uiou] @ hT^T per type, h16x4 interleaved ---------
__global__ __launch_bounds__(256,3) void gt16_mfma(const h16* __restrict__ hT,
    const h16* __restrict__ Wfrag, const float* __restrict__ biou,
    const float* __restrict__ Ufb, h16* __restrict__ GT16){
  __shared__ h16 ldsA[4*8*64*8];   // 32 KB
  __shared__ h16 ldsB[16*64*8];    // 16 KB
  const int t = threadIdx.x, w = t >> 6, l = t & 63;
  const int q = l >> 4, li = l & 15;
  const int waveR = w & 1, waveC = w >> 1;
  const int bx = blockIdx.x;

  {
    const int grow = bx*64 + w*16 + li;
    const size_t abase = (size_t)grow * 256;
    #pragma unroll
    for (int kc=0; kc<8; ++kc)
      DMA16(hT + abase + kc*32 + q*8, &ldsA[(w*8 + kc)*512]);
  }

  for (int cb=0; cb<4; ++cb){
    const h16* wfBase = Wfrag + (size_t)cb*8*16*512 + (size_t)l*8;

    #pragma unroll
    for (int i=0; i<4; ++i)
      DMA16(wfBase + ((size_t)(w*4 + i))*512, &ldsB[(w*4 + i)*512]);
    __syncthreads();

    f32x4 acc[4][2][2] = {};
    #pragma unroll
    for (int kc=0; kc<8; ++kc){
      f16x8 aF[2], bF[4][2];
      #pragma unroll
      for (int rt=0; rt<2; ++rt)
        aF[rt] = *(const f16x8*)&ldsA[(((waveR*2 + rt)*8 + kc)*64 + l)*8];
      #pragma unroll
      for (int g=0; g<4; ++g)
        #pragma unroll
        for (int ct=0; ct<2; ++ct)
          bF[g][ct] = *(const f16x8*)&ldsB[((g*4 + waveC*2 + ct)*64 + l)*8];
      __syncthreads();
      if (kc < 7){
        #pragma unroll
        for (int i=0; i<4; ++i)
          DMA16(wfBase + ((size_t)(kc+1)*16 + w*4 + i)*512,
                &ldsB[(w*4 + i)*512]);
      }
      #pragma unroll
      for (int g=0; g<4; ++g)
        #pragma unroll
        for (int rt=0; rt<2; ++rt)
          #pragma unroll
          for (int ct=0; ct<2; ++ct)
            acc[g][rt][ct] = __builtin_amdgcn_mfma_f32_16x16x32_f16(
                aF[rt], bF[g][ct], acc[g][rt][ct], 0,0,0);
      __syncthreads();
    }

    #pragma unroll
    for (int ct=0; ct<2; ++ct){
      const int c = cb*64 + waveC*32 + ct*16 + li;
      const float fb  = Ufb[c];
      const float bi2 = 0.5f*biou[c], bo2 = 0.5f*biou[256+c], bu2 = 0.5f*biou[512+c];
      #pragma unroll
      for (int rt=0; rt<2; ++rt){
        #pragma unroll
        for (int reg=0; reg<4; ++reg){
          const int row = bx*64 + waveR*32 + rt*16 + q*4 + reg;
          h16x4 o;
          o[0] = (h16)(acc[0][rt][ct][reg] + fb);
          o[1] = (h16)(acc[1][rt][ct][reg] + bi2);
          o[2] = (h16)(acc[2][rt][ct][reg] + bo2);
          o[3] = (h16)(acc[3][rt][ct][reg] + bu2);
          *(h16x4*)&GT16[(size_t)row*1024 + c*4] = o;
        }
      }
    }
  }
}

// ------------- lvl8: gather+cell + leaf-rep + parent-rep fold ---------------
__global__ __launch_bounds__(256) void lvl8_cell(const int* __restrict__ t1,
    const int* __restrict__ t2, const h16* __restrict__ GT16,
    const h16* __restrict__ cT, const h16* __restrict__ hT,
    h16* __restrict__ hUpHigh, h16* __restrict__ cPar,
    float* __restrict__ rep){
  const int k = threadIdx.x;
  const int m0 = blockIdx.x*32;
  const int rr = m0 >> 8;
  const int* tp = (rr < 128) ? t1 : t2;
  const int b = rr & 127;
  float s = 0.f;
  #pragma unroll 8
  for (int p=0; p<32; ++p){
    const int m = m0 + p, jn = m & 255;
    const size_t vl = (size_t)tp[b*NTREE + 511 + 2*jn];
    const size_t vr = (size_t)tp[b*NTREE + 512 + 2*jn];
    const h16x4 gl = *(const h16x4*)&GT16[vl*1024 + k*4];
    const h16x4 gr = *(const h16x4*)&GT16[vr*1024 + k*4];
    const float cl = (float)cT[vl*256 + k];
    const float cr = (float)cT[vr*256 + k];
    const float fl = sigf((float)gl[0]);
    const float fr = sigf((float)gr[0]);
    const float iv = (float)gl[1] + (float)gr[1];
    const float ov = (float)gl[2] + (float)gr[2];
    const float uv = (float)gl[3] + (float)gr[3];
    const float cnew = sig_mul_tanh(iv, uv) + fl*cl + fr*cr;
    const float hnew = sig_mul_tanh(ov, cnew);
    hUpHigh[((size_t)jn*256 + rr)*256 + k] = (h16)hnew;
    cPar[(size_t)m*256 + k] = (h16)cnew;
    s += (float)hT[vl*256 + k] + (float)hT[vr*256 + k] + hnew;  // leaves + parent
  }
  atomicAdd(&rep[rr*HS + k], s);
}

// ------------- level kernel (non-leaf levels, proven R18 schedule) ----------
// repFold (log2n>=5 only): rr2 = (bx*32)>>log2n is block-constant; fold
// per-thread h-sums into ldsRep[256] (R24 proven: plain inline atomicAdd,
// 8-way contention — cheaper than shfl_xor's ds_permute on the lgkm pipe,
// R25 measured 77.1 vs 91.2us), one global atomicAdd per (block,col).
__global__ __launch_bounds__(256,3) void level_mfma(
    const h16* __restrict__ hChild, const h16* __restrict__ cChild,
    const h16* __restrict__ Wfrag,   // [cb=4][kc=8][f=16][lane=64][8]
    const float* __restrict__ biou, const float* __restrict__ Ufb,
    h16* __restrict__ hUpW, h16* __restrict__ cPar, float* __restrict__ rep,
    int log2n, int cbN, int cOff, int ndOff, int repFold){
  const int n = 1 << log2n;
  const int mask2 = 2*n - 1;
  __shared__ h16 ldsA[4*8*64*8];   // 32 KB
  __shared__ h16 ldsB[16*64*8];    // 16 KB
  __shared__ float ldsRep[256];    //  1 KB
  const int t = threadIdx.x, w = t >> 6, l = t & 63;
  const int q = l >> 4, li = l & 15;
  const int waveR = w & 1, waveC = w >> 1;
  const int bx = blockIdx.x;

  if (repFold) ldsRep[t] = 0.f;    // first __syncthreads orders vs epilogue

  // ---- stage A once: wave w stages rowFrag R=w, kc=0..7 (frag-order) ----
  {
    const int grow = bx*64 + w*16 + li;
    const int cidx = grow & mask2;
    const int rr   = grow >> (log2n + 1);
    const size_t abase = ((size_t)(cOff + cidx)*256 + rr)*256;
    #pragma unroll
    for (int kc=0; kc<8; ++kc)
      DMA16(hChild + abase + kc*32 + q*8, &ldsA[(w*8 + kc)*512]);
  }

  for (int cb=0; cb<cbN; ++cb){
    const int cbi = blockIdx.y*cbN + cb;            // 64-col group 0..3
    const int colBase = cbi*64;
    const h16* wfBase = Wfrag + (size_t)cbi*8*16*512 + (size_t)l*8;

    // prologue: DMA B(kc=0)
    #pragma unroll
    for (int i=0; i<4; ++i)
      DMA16(wfBase + ((size_t)(w*4 + i))*512, &ldsB[(w*4 + i)*512]);
    __syncthreads();   // drains A-DMA (cb==0) + B(0) + prior epilogue reads

    f32x4 acc[4][2][2] = {};   // [gate f,i,o,u][rt][ct]
    #pragma unroll
    for (int kc=0; kc<8; ++kc){
      f16x8 aF[2], bF[4][2];
      #pragma unroll
      for (int rt=0; rt<2; ++rt)
        aF[rt] = *(const f16x8*)&ldsA[(((waveR*2 + rt)*8 + kc)*64 + l)*8];
      #pragma unroll
      for (int g=0; g<4; ++g)
        #pragma unroll
        for (int ct=0; ct<2; ++ct)
          bF[g][ct] = *(const f16x8*)&ldsB[((g*4 + waveC*2 + ct)*64 + l)*8];
      __syncthreads();   // all reads done
      if (kc < 7){
        #pragma unroll
        for (int i=0; i<4; ++i)
          DMA16(wfBase + ((size_t)(kc+1)*16 + w*4 + i)*512,
                &ldsB[(w*4 + i)*512]);
      }
      #pragma unroll
      for (int g=0; g<4; ++g)
        #pragma unroll
        for (int rt=0; rt<2; ++rt)
          #pragma unroll
          for (int ct=0; ct<2; ++ct)
            acc[g][rt][ct] = __builtin_amdgcn_mfma_f32_16x16x32_f16(
                aF[rt], bF[g][ct], acc[g][rt][ct], 0,0,0);
      __syncthreads();   // drains B(kc+1)
    }

    // ---- epilogue (all lane-local; sibling pairs = adjacent C regs) ----
    #pragma unroll
    for (int ct=0; ct<2; ++ct){
      const int c = colBase + waveC*32 + ct*16 + li;
      const float fb  = Ufb[c];
      const float bi_ = biou[c], bo_ = biou[256+c], bu_ = biou[512+c];
      float rsum = 0.f;
      #pragma unroll
      for (int rt=0; rt<2; ++rt){
        #pragma unroll
        for (int pp=0; pp<2; ++pp){
          const int crel = waveR*32 + rt*16 + q*4 + 2*pp;  // even child row (rel)
          const int m = bx*32 + (crel >> 1);               // global parent index
          const int rr2 = m >> log2n;
          const int jn = m & (n - 1);
          const float cl = (float)cChild[(size_t)(bx*64 + crel)*256 + c];
          const float cr = (float)cChild[(size_t)(bx*64 + crel + 1)*256 + c];
          const float fl = sigf(acc[0][rt][ct][2*pp]   + fb);
          const float fr = sigf(acc[0][rt][ct][2*pp+1] + fb);
          const float iv = acc[1][rt][ct][2*pp] + acc[1][rt][ct][2*pp+1] + bi_;
          const float ov = acc[2][rt][ct][2*pp] + acc[2][rt][ct][2*pp+1] + bo_;
          const float uv = acc[3][rt][ct][2*pp] + acc[3][rt][ct][2*pp+1] + bu_;
          const float cnew = sig_mul_tanh(iv, uv) + fl*cl + fr*cr;
          const float hnew = sig_mul_tanh(ov, cnew);
          hUpW[(((size_t)(ndOff + jn))*256 + rr2)*256 + c] = (h16)hnew;
          cPar[((size_t)m)*256 + c] = (h16)cnew;
          rsum += hnew;
        }
      }
      if (repFold) atomicAdd(&ldsRep[c], rsum);
    }
  }

  if (repFold){
    __syncthreads();
    atomicAdd(&rep[((bx*32) >> log2n)*HS + t], ldsRep[t]);
  }
}

// ------------- rep accumulation (lvl<=4 outputs, nodes 0..30 only) ----------
__global__ __launch_bounds__(256) void rep_accum(const h16* __restrict__ H,
    float* __restrict__ rep, int nrows, int chunk){
  const int r = blockIdx.y, k = threadIdx.x;
  const int n0 = blockIdx.x * chunk;
  int n1 = n0 + chunk; if (n1 > nrows) n1 = nrows;
  float s = 0.f;
  for (int nd = n0; nd < n1; ++nd)
    s += (float)H[((size_t)nd*256 + r)*HS + k];
  atomicAdd(&rep[r*HS + k], s);
}

// ------------- classifier -------------
__global__ __launch_bounds__(256) void cls_kernel(const float* __restrict__ rep,
    const float* __restrict__ clsw, const float* __restrict__ clsb,
    float* __restrict__ out){
  const int b = blockIdx.x, k = threadIdx.x;
  const float d = fabsf(rep[b*HS + k] - rep[(128+b)*HS + k]) * (1.0f/1023.0f);
  __shared__ float r0[256], r1[256];
  r0[k] = d * clsw[k];
  r1[k] = d * clsw[HS + k];
  __syncthreads();
  for (int off = 128; off > 0; off >>= 1){
    if (k < off){ r0[k] += r0[k+off]; r1[k] += r1[k+off]; }
    __syncthreads();
  }
  if (k == 0){
    out[b*2 + 0] = r0[0] + clsb[0];
    out[b*2 + 1] = r1[0] + clsb[1];
  }
}

extern "C" void kernel_launch(void* const* d_in, const int* in_sizes, int n_in,
                              void* d_out, int out_size, void* d_ws, size_t ws_size,
                              hipStream_t stream){
  const int*   types1 = (const int*)d_in[0];
  const int*   types2 = (const int*)d_in[1];
  const float* emb    = (const float*)d_in[2];
  const float* Wiou   = (const float*)d_in[3];
  const float* Uiou   = (const float*)d_in[4];
  const float* biou   = (const float*)d_in[5];
  const float* Ufw    = (const float*)d_in[6];
  const float* Ufb    = (const float*)d_in[7];
  const float* clsw   = (const float*)d_in[8];
  const float* clsb   = (const float*)d_in[9];
  float* out = (float*)d_out;

  // ---- overlay layout (h16 units). Total 116,588,544 h16 = 233.18 MB ----
  h16* ws      = (h16*)d_ws;
  // GT16 [0, 32,768,000) overlays emb16 (dead after ht_mfma);
  // hUpLow+cB overlay GT16 (dead after lvl8_cell).
  h16* GT16    = ws;                         // 32,768,000 h16 = 65.5 MB
  h16* emb16   = ws + 24576000UL;            //  8,192,000
  h16* Wx16    = ws + 32768000UL;            //    196,608 (dead after swizzle)
  h16* hUpLow  = ws;                         // 16,711,680 (nodes 0..254)
  h16* cB      = ws + 16711680UL;            //  8,388,608
  h16* hT      = ws + 65536000UL;            //  8,192,000
  h16* cT      = ws + 73728000UL;            //  8,192,000
  h16* hUpHigh = ws + 81920000UL;            // 16,777,216 (nodes 255..510 local)
  h16* cA      = ws + 98697216UL;            // 16,777,216
  h16* W16     = ws + 115474432UL;           //    262,144
  h16* Wfrag   = ws + 115736576UL;           //    524,288
  float* rep   = (float*)(ws + 116260864UL); //     65,536 f32
  h16* WxFrag  = ws + 116391936UL;           //    196,608

  convert_all<<<4224, 256, 0, stream>>>(emb, Ufw, Uiou, Wiou, emb16, W16, Wx16, rep);
  swizzle_all<<<352, 256, 0, stream>>>(W16, Wx16, Wfrag, WxFrag);
  ht_mfma<<<500, 256, 0, stream>>>(emb16, WxFrag, biou, hT, cT);
  gt16_mfma<<<500, 256, 0, stream>>>(hT, Wfrag, biou, Ufb, GT16); // overwrites emb16
  lvl8_cell<<<2048, 256, 0, stream>>>(types1, types2, GT16, cT, hT,
                                      hUpHigh, cA, rep);

  const h16* cprev = cA;
  for (int lvl = 7; lvl >= 0; --lvl){
    const int children = 512 << lvl;        // B2 * 2n
    const int cbN = (lvl >= 6) ? 4 : 1;     // big levels: y=1, col loop in-block
    h16* cout = ((8 - lvl) & 1) ? cB : cA;
    const h16* hin = (lvl == 7) ? hUpHigh : hUpLow;
    const int cOff  = (lvl == 7) ? 0 : ((1 << (lvl + 1)) - 1);
    const int ndOff = (1 << lvl) - 1;
    const int repFold = (lvl >= 5) ? 1 : 0; // rr2 block-constant iff log2n>=5
    level_mfma<<<dim3(children/64, 4/cbN), 256, 0, stream>>>(
        hin, cprev, Wfrag, biou, Ufb, hUpLow, cout, rep,
        lvl, cbN, cOff, ndOff, repFold);
    cprev = cout;
  }
  // only lvl<=4 outputs (nodes 0..30) still need scanning
  rep_accum<<<dim3(1, B2), 256, 0, stream>>>(hUpLow, rep, 31, 31);
  cls_kernel<<<128, 256, 0, stream>>>(rep, clsw, clsb, out);
}